// Round 6
// baseline (887.836 us; speedup 1.0000x reference)
//
#include <hip/hip_runtime.h>
#include <hip/hip_bf16.h>

typedef __hip_bfloat16 bf16;
typedef __attribute__((ext_vector_type(8))) short short8v;
typedef __attribute__((ext_vector_type(4))) float f32x4;

#define N_   4
#define C_   256
#define CC_  96
#define HH   128
#define WHH  128
#define HL   64
#define WL   64
#define PH   (HH*WHH)   // 16384
#define PL   (HL*WL)    // 4096

// ---- ws layout (float offsets) ----
#define WF_HRC   16
#define WF_LRC   (WF_HRC+24576)
#define WF_ENC   (WF_LRC+24576)
#define WF_ENC2  (WF_ENC+21600)
#define WF_PROJ  (WF_ENC2+7776)
#define B_HRC    (WF_PROJ+24576)
#define B_LRC    (B_HRC+96)
#define B_ENC    (B_LRC+96)
#define B_ENC2   (B_ENC+25)
#define B_PROJ   (B_ENC2+9)
#define HAM_LF   (B_PROJ+96)
#define HAM_HF   (HAM_LF+25)
// bf16 weight region (u16 units, based at ws + WBF_BASE floats)
#define WBF_BASE 103488
#define WB_HRC   0
#define WB_LRC   24576
#define WB_PROJ  49152
// f32 activation scratch
#define A_CHR    140416
#define A_CHR2   (A_CHR + 6291456)
#define A_CLR    (A_CHR2 + 6291456)
#define A_MHH    (A_CLR + 1572864)
#define A_MLH    (A_MHH + 589824)
#define A_MASKLR (A_MLH + 1638400)
#define A_MLL    (A_MASKLR + 1638400)
#define A_MHL    (A_MLL + 409600)
#define A_MLRN   (A_MHL + 147456)
#define A_MHRN   (A_MLRN + 1638400)
#define A_LRUP   (A_MHRN + 589824)
#define WS_FLOATS (A_LRUP + 16777216)

// partial-sum scratch (reused regions; valid by liveness)
#define P_MHH  A_CHR2
#define P_MLH  (A_LRUP)
#define P_MLL  (A_LRUP + 7000000)
#define P_MHL  (A_LRUP + 11000000)

#define OUT0_OFF 0L
#define OUT1_OFF 1638400L
#define OUT2_OFF (1638400L + 16777216L)

__device__ __forceinline__ float ldin(const void* p, long i, int isbf) {
    if (isbf) return __bfloat162float(((const bf16*)p)[i]);
    return ((const float*)p)[i];
}

// Detect input dtype: hamming_hfqg center element == 1.0.
__global__ void probe_dtype(const void* hamhf, int* flag) {
    const unsigned short* u = (const unsigned short*)hamhf;
    *flag = (u[4] == 0x3F80u) ? 1 : 0;
}

// Fused weight/bias conversion.
// mode 0: f32 copy. mode 1: (96,256) -> transposed f32 [c][o]. mode 2: bf16 copy (u16 region).
struct Seg { const void* src; int dst; int n; int mode; };
struct SegsN { Seg s[15]; };

__global__ __launch_bounds__(256) void cvt_all(SegsN A, float* ws,
                                               const int* __restrict__ flag, int total) {
    int isbf = *flag;
    int i = blockIdx.x * 256 + threadIdx.x;
    if (i >= total) return;
    int k = 0, j = i;
    while (j >= A.s[k].n) { j -= A.s[k].n; ++k; }
    float v = ldin(A.s[k].src, j, isbf);
    if (A.s[k].mode == 2) {
        bf16 h = __float2bfloat16(v);
        ((unsigned short*)(ws + WBF_BASE))[A.s[k].dst + j] = *(unsigned short*)&h;
    } else if (A.s[k].mode == 1) {
        int o = j >> 8, c = j & 255;
        ws[A.s[k].dst + c * 96 + o] = v;
    } else {
        ws[A.s[k].dst + j] = v;
    }
}

// ---------------- MFMA path (bf16 inputs) ----------------
// C[n][m][p] = bias[m] + sum_k W[m][k]*X[n][k][p].  M=96, K=256, per-block 256-px tile.
// LDS: X K-slice [32][pitch 260] u16. A-frag: row=l&15,k=(l>>4)*8+j. D: col=l&15,row=(l>>4)*4+r.
__global__ __launch_bounds__(256) void conv1x1_mfma(
    const unsigned short* __restrict__ X, const float* __restrict__ ws_base,
    int wb_off, const float* __restrict__ bias, float* __restrict__ C, int P,
    const int* __restrict__ flag, int gate)
{
    if (*flag != gate) return;
    const unsigned short* Wb = (const unsigned short*)(ws_base + WBF_BASE) + wb_off;
    __shared__ unsigned short lds[32 * 260];
    int t = threadIdx.x;
    int lane = t & 63, wave = t >> 6;
    int l15 = lane & 15, l4 = lane >> 4;
    int p0 = blockIdx.x * 256;
    int n = blockIdx.y;
    const unsigned short* Xn = X + (long)n * C_ * P + p0;

    f32x4 acc[6][4];
#pragma unroll
    for (int mi = 0; mi < 6; mi++)
#pragma unroll
        for (int ni = 0; ni < 4; ni++) acc[mi][ni] = (f32x4)0.f;

    int r = t >> 3, c0 = (t & 7) * 32;
    for (int ks = 0; ks < 8; ++ks) {
        // stage X[ks*32 .. +32)[p0 .. +256) -> lds[32][260]
        const unsigned short* src = Xn + (long)(ks * 32 + r) * P + c0;
        unsigned short* dst = lds + r * 260 + c0;
#pragma unroll
        for (int i = 0; i < 8; i++)
            *(uint2*)(dst + i * 4) = *(const uint2*)(src + i * 4);
        __syncthreads();

        short8v a[6];
#pragma unroll
        for (int mi = 0; mi < 6; mi++)
            a[mi] = *(const short8v*)(Wb + (mi * 16 + l15) * 256 + ks * 32 + l4 * 8);
#pragma unroll
        for (int ni = 0; ni < 4; ni++) {
            short8v b;
            int p = wave * 64 + ni * 16 + l15;
#pragma unroll
            for (int j = 0; j < 8; j++)
                b[j] = (short)lds[(l4 * 8 + j) * 260 + p];
#pragma unroll
            for (int mi = 0; mi < 6; mi++)
                acc[mi][ni] = __builtin_amdgcn_mfma_f32_16x16x32_bf16(a[mi], b, acc[mi][ni], 0, 0, 0);
        }
        __syncthreads();
    }
#pragma unroll
    for (int mi = 0; mi < 6; mi++)
#pragma unroll
        for (int ni = 0; ni < 4; ni++) {
            int p = p0 + wave * 64 + ni * 16 + l15;
#pragma unroll
            for (int rr = 0; rr < 4; rr++) {
                int m = mi * 16 + l4 * 4 + rr;
                C[((long)n * CC_ + m) * P + p] = acc[mi][ni][rr] + bias[m];
            }
        }
}

// ---------------- VALU fallback path (f32 inputs) ----------------
__global__ __launch_bounds__(256) void conv1x1_in(
    const void* __restrict__ x, const float* __restrict__ WT, const float* __restrict__ bfp,
    float* __restrict__ y, int P, const int* __restrict__ flag, int gate)
{
    if (*flag != gate) return;
    int isbf = *flag;
    int g = blockIdx.x * 256 + threadIdx.x;
    int n = g / P, p = g - n * P;
    int cc0 = blockIdx.y * 48;
    long xoff = (long)n * C_ * P + p;
    float acc[48];
#pragma unroll
    for (int i = 0; i < 48; i++) acc[i] = 0.f;
    for (int c = 0; c < C_; ++c) {
        float xv = ldin(x, xoff + (long)c * P, isbf);
        const float* wr = WT + c * 96 + cc0;
#pragma unroll
        for (int i = 0; i < 48; i++) acc[i] = fmaf(wr[i], xv, acc[i]);
    }
    float* yb = y + ((long)n * CC_ + cc0) * P + p;
#pragma unroll
    for (int i = 0; i < 48; i++) yb[(long)i * P] = acc[i] + bfp[cc0 + i];
}

__global__ __launch_bounds__(256) void conv1x1_proj(
    const float* __restrict__ x, const float* __restrict__ WT, const float* __restrict__ bfp,
    float* __restrict__ yout, long obase, const int* __restrict__ flag, int gate)
{
    if (*flag != gate) return;
    int g = blockIdx.x * 256 + threadIdx.x;
    int n = g / PH, p = g - n * PH;
    int cc0 = blockIdx.y * 48;
    const float* xb = x + (long)n * C_ * PH + p;
    float acc[48];
#pragma unroll
    for (int i = 0; i < 48; i++) acc[i] = 0.f;
    for (int c = 0; c < C_; ++c) {
        float xv = xb[(long)c * PH];
        const float* wr = WT + c * 96 + cc0;
#pragma unroll
        for (int i = 0; i < 48; i++) acc[i] = fmaf(wr[i], xv, acc[i]);
    }
    float* yb = yout + obase + ((long)n * CC_ + cc0) * PH + p;
#pragma unroll
    for (int i = 0; i < 48; i++) yb[(long)i * PH] = acc[i] + bfp[cc0 + i];
}

// ---------------- 3x3 convs (K-split direct) ----------------
template<int COUT>
__global__ __launch_bounds__(256) void conv3x3_part_k(
    const float* __restrict__ x, const float* __restrict__ Wf,
    float* __restrict__ part, int H, int W, int KC)
{
    int p = blockIdx.x * 256 + threadIdx.x;
    int n = blockIdx.y, ks = blockIdx.z;
    int HW = H * W;
    int gy = p / W, gx = p - gy * W;
    int c0 = ks * KC;
    const float* xb = x + ((long)n * CC_ + c0) * HW + p;
    float acc[COUT];
#pragma unroll
    for (int o = 0; o < COUT; o++) acc[o] = 0.f;
    for (int c = 0; c < KC; ++c) {
        const float* xc = xb + (long)c * HW;
        float v[9];
#pragma unroll
        for (int t = 0; t < 9; t++) {
            int dy = t / 3 - 1, dx = t % 3 - 1;
            int yy = gy + dy, xx = gx + dx;
            v[t] = (yy >= 0 && yy < H && xx >= 0 && xx < W) ? xc[dy * W + dx] : 0.f;
        }
        const float* wc = Wf + (c0 + c) * 9;
#pragma unroll
        for (int o = 0; o < COUT; o++)
#pragma unroll
            for (int t = 0; t < 9; t++)
                acc[o] = fmaf(wc[(long)o * CC_ * 9 + t], v[t], acc[o]);
    }
    float* pb = part + ((long)ks * N_ + n) * COUT * HW + p;
#pragma unroll
    for (int o = 0; o < COUT; o++) pb[(long)o * HW] = acc[o];
}

__global__ __launch_bounds__(256) void reduce_part(
    const float* __restrict__ part, const float* __restrict__ bias,
    float* __restrict__ out, int KS, long kstride, int COUT, int HW, int total)
{
    int g = blockIdx.x * 256 + threadIdx.x;
    if (g >= total) return;
    float s = 0.f;
    for (int k = 0; k < KS; k++) s += part[(long)k * kstride + g];
    out[g] = s + bias[(g / HW) % COUT];
}

// ---------------- CARAFE / mask kernels ----------------
__global__ __launch_bounds__(256) void carafe3_res_d(
    const float* __restrict__ x, const float* __restrict__ m,
    const float* __restrict__ hamf, float* __restrict__ y, int KC)
{
    int p = blockIdx.x * 256 + threadIdx.x;
    int n = blockIdx.y;
    int c0 = blockIdx.z * KC;
    int gy = p >> 7, gx = p & 127;
    const float* mb = m + (long)n * 9 * PH + p;
    float w[9]; float mx = -1e30f;
#pragma unroll
    for (int t = 0; t < 9; t++) { w[t] = mb[(long)t * PH]; mx = fmaxf(mx, w[t]); }
    float s = 0.f;
#pragma unroll
    for (int t = 0; t < 9; t++) { w[t] = __expf(w[t] - mx) * hamf[t]; s += w[t]; }
    float inv = 1.f / s;
#pragma unroll
    for (int t = 0; t < 9; t++) w[t] *= inv;
    for (int c = c0; c < c0 + KC; ++c) {
        const float* xc = x + ((long)n * CC_ + c) * PH + p;
        float acc = 0.f, ctr = xc[0];
#pragma unroll
        for (int t = 0; t < 9; t++) {
            int dy = t / 3 - 1, dx = t % 3 - 1;
            int yy = gy + dy, xx = gx + dx;
            float v = (yy >= 0 && yy < HH && xx >= 0 && xx < WHH) ? xc[dy * WHH + dx] : 0.f;
            acc = fmaf(v, w[t], acc);
        }
        y[((long)n * CC_ + c) * PH + p] = 2.f * ctr - acc;
    }
}

__global__ __launch_bounds__(256) void fuse_masklr(
    const float* __restrict__ mlh, const float* __restrict__ mll,
    const float* __restrict__ hamf, float* __restrict__ masklr)
{
    __shared__ float tile[25 * 144];
    int bx = blockIdx.x & 7, by = blockIdx.x >> 3;
    int n = blockIdx.y;
    int ox = threadIdx.x & 15, oy = threadIdx.x >> 4;
    int gx = bx * 16 + ox, gy = by * 16 + oy;
    const float* mb = mlh + (long)n * 25 * PH + gy * WHH + gx;
    float mv[25], w[25]; float mx = -1e30f;
#pragma unroll
    for (int t = 0; t < 25; t++) { mv[t] = mb[(long)t * PH]; mx = fmaxf(mx, mv[t]); }
    float s = 0.f;
#pragma unroll
    for (int t = 0; t < 25; t++) { w[t] = __expf(mv[t] - mx) * hamf[t]; s += w[t]; }
    float inv = 1.f / s;
#pragma unroll
    for (int t = 0; t < 25; t++) w[t] *= inv;
    int iy0 = by * 8 - 2, ix0 = bx * 8 - 2;
    const float* xn = mll + (long)n * 25 * PL;
    for (int i = threadIdx.x; i < 25 * 144; i += 256) {
        int c = i / 144, rr = i - c * 144;
        int ty = rr / 12, tx = rr - ty * 12;
        int sy = iy0 + ty, sx = ix0 + tx;
        tile[i] = (sy >= 0 && sy < HL && sx >= 0 && sx < WL) ? xn[((long)c * HL + sy) * WL + sx] : 0.f;
    }
    __syncthreads();
    int ly = oy >> 1, lx = ox >> 1;
    float* yb = masklr + (long)n * 25 * PH + gy * WHH + gx;
#pragma unroll
    for (int c = 0; c < 25; c++) {
        float acc = mv[c];
        const float* tc = tile + c * 144;
#pragma unroll
        for (int p = 0; p < 5; p++)
#pragma unroll
            for (int q = 0; q < 5; q++)
                acc = fmaf(tc[(ly + p) * 12 + lx + q], w[p * 5 + q], acc);
        yb[(long)c * PH] = acc;
    }
}

__global__ __launch_bounds__(256) void norm_lr_out(
    const float* __restrict__ masklr, const float* __restrict__ hamf,
    float* __restrict__ mlrn, float* __restrict__ out0)
{
    int g = blockIdx.x * 256 + threadIdx.x;
    int n = g / PH, p = g - n * PH;
    const float* mb = masklr + (long)n * 25 * PH + p;
    float v[25]; float mx = -1e30f;
#pragma unroll
    for (int t = 0; t < 25; t++) { v[t] = mb[(long)t * PH]; mx = fmaxf(mx, v[t]); }
    float s = 0.f;
#pragma unroll
    for (int t = 0; t < 25; t++) { v[t] = __expf(v[t] - mx) * hamf[t]; s += v[t]; }
    float inv = 1.f / s;
    float* ob = mlrn + (long)n * 25 * PH + p;
    float* o2 = out0 + (long)n * 25 * PH + p;
#pragma unroll
    for (int t = 0; t < 25; t++) {
        float rr = v[t] * inv;
        ob[(long)t * PH] = rr;
        o2[(long)t * PH] = rr;
    }
}

__global__ __launch_bounds__(256) void fuse_maskhr(
    const float* __restrict__ mhh, const float* __restrict__ mhl,
    const float* __restrict__ mlrn, const float* __restrict__ hamhf,
    float* __restrict__ mhrn)
{
    __shared__ float tile[9 * 144];
    int bx = blockIdx.x & 7, by = blockIdx.x >> 3;
    int n = blockIdx.y;
    int ox = threadIdx.x & 15, oy = threadIdx.x >> 4;
    int gx = bx * 16 + ox, gy = by * 16 + oy;
    const float* wb = mlrn + (long)n * 25 * PH + gy * WHH + gx;
    float w[25];
#pragma unroll
    for (int t = 0; t < 25; t++) w[t] = wb[(long)t * PH];
    int iy0 = by * 8 - 2, ix0 = bx * 8 - 2;
    const float* xn = mhl + (long)n * 9 * PL;
    for (int i = threadIdx.x; i < 9 * 144; i += 256) {
        int c = i / 144, rr = i - c * 144;
        int ty = rr / 12, tx = rr - ty * 12;
        int sy = iy0 + ty, sx = ix0 + tx;
        tile[i] = (sy >= 0 && sy < HL && sx >= 0 && sx < WL) ? xn[((long)c * HL + sy) * WL + sx] : 0.f;
    }
    __syncthreads();
    int ly = oy >> 1, lx = ox >> 1;
    const float* hb = mhh + (long)n * 9 * PH + gy * WHH + gx;
    float v[9]; float mx = -1e30f;
#pragma unroll
    for (int c = 0; c < 9; c++) {
        float acc = hb[(long)c * PH];
        const float* tc = tile + c * 144;
#pragma unroll
        for (int p = 0; p < 5; p++)
#pragma unroll
            for (int q = 0; q < 5; q++)
                acc = fmaf(tc[(ly + p) * 12 + lx + q], w[p * 5 + q], acc);
        v[c] = acc; mx = fmaxf(mx, acc);
    }
    float s = 0.f;
#pragma unroll
    for (int c = 0; c < 9; c++) { v[c] = __expf(v[c] - mx) * hamhf[c]; s += v[c]; }
    float inv = 1.f / s;
    float* ob = mhrn + (long)n * 9 * PH + gy * WHH + gx;
#pragma unroll
    for (int c = 0; c < 9; c++) ob[(long)c * PH] = v[c] * inv;
}

__global__ __launch_bounds__(256) void hr_out_d(
    const void* __restrict__ hr, const float* __restrict__ mhrn,
    float* __restrict__ out, long obase, const int* __restrict__ flag, int KC)
{
    int isbf = *flag;
    int p = blockIdx.x * 256 + threadIdx.x;
    int n = blockIdx.y;
    int c0 = blockIdx.z * KC;
    int gy = p >> 7, gx = p & 127;
    const float* mb = mhrn + (long)n * 9 * PH + p;
    float w[9];
#pragma unroll
    for (int t = 0; t < 9; t++) w[t] = mb[(long)t * PH];
    for (int c = c0; c < c0 + KC; ++c) {
        long cb = ((long)n * C_ + c) * PH + p;
        float ctr = ldin(hr, cb, isbf);
        float acc = 0.f;
#pragma unroll
        for (int t = 0; t < 9; t++) {
            int dy = t / 3 - 1, dx = t % 3 - 1;
            int yy = gy + dy, xx = gx + dx;
            float v = (yy >= 0 && yy < HH && xx >= 0 && xx < WHH) ? ldin(hr, cb + dy * WHH + dx, isbf) : 0.f;
            acc = fmaf(v, w[t], acc);
        }
        out[obase + cb] = 2.f * ctr - acc;
    }
}

// lr_up: writes bf16 (flag=1, consumed by MFMA proj) or f32 (flag=0, VALU proj).
__global__ __launch_bounds__(256) void lr_up_d(
    const void* __restrict__ lrf, const float* __restrict__ mlrn,
    float* __restrict__ lrup, const int* __restrict__ flag, int KC)
{
    int isbf = *flag;
    int p = blockIdx.x * 256 + threadIdx.x;
    int n = blockIdx.y;
    int c0 = blockIdx.z * KC;
    int gy = p >> 7, gx = p & 127;
    const float* wb = mlrn + (long)n * 25 * PH + p;
    float w[25];
#pragma unroll
    for (int t = 0; t < 25; t++) w[t] = wb[(long)t * PH];
    int iy0 = (gy >> 1) - 2, ix0 = (gx >> 1) - 2;
    for (int c = c0; c < c0 + KC; ++c) {
        long cb = ((long)n * C_ + c) * PL;
        float acc = 0.f;
#pragma unroll
        for (int py = 0; py < 5; py++) {
            int yy = iy0 + py;
#pragma unroll
            for (int qx = 0; qx < 5; qx++) {
                int xx = ix0 + qx;
                float v = (yy >= 0 && yy < HL && xx >= 0 && xx < WL) ? ldin(lrf, cb + yy * WL + xx, isbf) : 0.f;
                acc = fmaf(v, w[py * 5 + qx], acc);
            }
        }
        long oi = ((long)n * C_ + c) * PH + p;
        if (isbf) ((bf16*)lrup)[oi] = __float2bfloat16(acc);
        else lrup[oi] = acc;
    }
}

extern "C" void kernel_launch(void* const* d_in, const int* in_sizes, int n_in,
                              void* d_out, int out_size, void* d_ws, size_t ws_size,
                              hipStream_t stream)
{
    if (ws_size < (size_t)WS_FLOATS * 4) return;

    const void* hr    = d_in[0];
    const void* lrf   = d_in[1];
    const void* Whrc  = d_in[2];
    const void* bhrc  = d_in[3];
    const void* Wlrc  = d_in[4];
    const void* blrc  = d_in[5];
    const void* Wenc  = d_in[6];
    const void* benc  = d_in[7];
    const void* Wenc2 = d_in[8];
    const void* benc2 = d_in[9];
    const void* Wproj = d_in[10];
    const void* bproj = d_in[11];
    const void* hamlf = d_in[12];
    const void* hamhf = d_in[13];

    float* ws = (float*)d_ws;
    int* flag = (int*)d_ws;
    float* out = (float*)d_out;

    probe_dtype<<<1, 1, 0, stream>>>(hamhf, flag);

    SegsN A;
    A.s[0]  = {Whrc,  WF_HRC,  24576, 1};
    A.s[1]  = {Wlrc,  WF_LRC,  24576, 1};
    A.s[2]  = {Wproj, WF_PROJ, 24576, 1};
    A.s[3]  = {Wenc,  WF_ENC,  21600, 0};
    A.s[4]  = {Wenc2, WF_ENC2, 7776,  0};
    A.s[5]  = {bhrc,  B_HRC,   96,    0};
    A.s[6]  = {blrc,  B_LRC,   96,    0};
    A.s[7]  = {benc,  B_ENC,   25,    0};
    A.s[8]  = {benc2, B_ENC2,  9,     0};
    A.s[9]  = {bproj, B_PROJ,  96,    0};
    A.s[10] = {hamlf, HAM_LF,  25,    0};
    A.s[11] = {hamhf, HAM_HF,  9,     0};
    A.s[12] = {Whrc,  WB_HRC,  24576, 2};
    A.s[13] = {Wlrc,  WB_LRC,  24576, 2};
    A.s[14] = {Wproj, WB_PROJ, 24576, 2};
    int cvt_total = 24576*6 + 21600 + 7776 + 96*3 + 25 + 9 + 25 + 9;
    cvt_all<<<(cvt_total + 255) / 256, 256, 0, stream>>>(A, ws, flag, cvt_total);

    // c_hr, c_lr: MFMA path (bf16 inputs) + VALU fallback (f32 inputs)
    conv1x1_mfma<<<dim3(PH / 256, N_), 256, 0, stream>>>(
        (const unsigned short*)hr, ws, WB_HRC, ws + B_HRC, ws + A_CHR, PH, flag, 1);
    conv1x1_mfma<<<dim3(PL / 256, N_), 256, 0, stream>>>(
        (const unsigned short*)lrf, ws, WB_LRC, ws + B_LRC, ws + A_CLR, PL, flag, 1);
    conv1x1_in<<<dim3(N_ * PH / 256, 2), 256, 0, stream>>>(hr, ws + WF_HRC, ws + B_HRC, ws + A_CHR, PH, flag, 0);
    conv1x1_in<<<dim3(N_ * PL / 256, 2), 256, 0, stream>>>(lrf, ws + WF_LRC, ws + B_LRC, ws + A_CLR, PL, flag, 0);

    // m_hh = conv3x3(c_hr, W_enc2): K-split 4 x 24ch
    conv3x3_part_k<9><<<dim3(PH / 256, N_, 4), 256, 0, stream>>>(ws + A_CHR, ws + WF_ENC2, ws + P_MHH, HH, WHH, 24);
    reduce_part<<<(N_*9*PH + 255) / 256, 256, 0, stream>>>(ws + P_MHH, ws + B_ENC2, ws + A_MHH, 4, (long)N_*9*PH, 9, PH, N_*9*PH);

    // c_hr2 = 2*c_hr - carafe3(c_hr, norm(m_hh))
    carafe3_res_d<<<dim3(PH / 256, N_, 6), 256, 0, stream>>>(ws + A_CHR, ws + A_MHH, ws + HAM_HF, ws + A_CHR2, 16);

    // m_lh = conv3x3(c_hr2, W_enc): K-split 4 x 24ch
    conv3x3_part_k<25><<<dim3(PH / 256, N_, 4), 256, 0, stream>>>(ws + A_CHR2, ws + WF_ENC, ws + P_MLH, HH, WHH, 24);
    reduce_part<<<(N_*25*PH + 255) / 256, 256, 0, stream>>>(ws + P_MLH, ws + B_ENC, ws + A_MLH, 4, (long)N_*25*PH, 25, PH, N_*25*PH);

    // m_ll, m_hl on c_lr (64x64): K-split 8 x 12ch
    conv3x3_part_k<25><<<dim3(PL / 256, N_, 8), 256, 0, stream>>>(ws + A_CLR, ws + WF_ENC, ws + P_MLL, HL, WL, 12);
    reduce_part<<<(N_*25*PL + 255) / 256, 256, 0, stream>>>(ws + P_MLL, ws + B_ENC, ws + A_MLL, 8, (long)N_*25*PL, 25, PL, N_*25*PL);
    conv3x3_part_k<9><<<dim3(PL / 256, N_, 8), 256, 0, stream>>>(ws + A_CLR, ws + WF_ENC2, ws + P_MHL, HL, WL, 12);
    reduce_part<<<(N_*9*PL + 255) / 256, 256, 0, stream>>>(ws + P_MHL, ws + B_ENC2, ws + A_MHL, 8, (long)N_*9*PL, 9, PL, N_*9*PL);

    // mask_lr = m_lh + carafe_up2(m_ll, norm(m_lh))
    fuse_masklr<<<dim3(64, N_), 256, 0, stream>>>(ws + A_MLH, ws + A_MLL, ws + HAM_LF, ws + A_MASKLR);
    // mask_lr_n (== mask_lr_init2) -> scratch f32 + output0 f32
    norm_lr_out<<<dim3(N_ * PH / 256), 256, 0, stream>>>(ws + A_MASKLR, ws + HAM_LF, ws + A_MLRN, out);
    // mask_hr_n = norm(m_hh + carafe_up2(m_hl, mask_lr_n))
    fuse_maskhr<<<dim3(64, N_), 256, 0, stream>>>(ws + A_MHH, ws + A_MHL, ws + A_MLRN, ws + HAM_HF, ws + A_MHRN);
    // hr_out -> output1
    hr_out_d<<<dim3(PH / 256, N_, 8), 256, 0, stream>>>(hr, ws + A_MHRN, out, OUT1_OFF, flag, 32);
    // lr_up = carafe_up2(lr_feat, mask_lr_n) -> bf16 (flag=1) or f32 (flag=0)
    lr_up_d<<<dim3(PH / 256, N_, 8), 256, 0, stream>>>(lrf, ws + A_MLRN, ws + A_LRUP, flag, 32);
    // lr_out = conv1x1(lr_up, W_proj) -> output2
    conv1x1_mfma<<<dim3(PH / 256, N_), 256, 0, stream>>>(
        (const unsigned short*)(ws + A_LRUP), ws, WB_PROJ, ws + B_PROJ, out + OUT2_OFF, PH, flag, 1);
    conv1x1_proj<<<dim3(N_ * PH / 256, 2), 256, 0, stream>>>(ws + A_LRUP, ws + WF_PROJ, ws + B_PROJ, out, OUT2_OFF, flag, 0);
}

// Round 7
// 570.398 us; speedup vs baseline: 1.5565x; 1.5565x over previous
//
#include <hip/hip_runtime.h>
#include <hip/hip_bf16.h>

typedef __hip_bfloat16 bf16;
typedef __attribute__((ext_vector_type(8))) short short8v;
typedef __attribute__((ext_vector_type(4))) float f32x4;

#define N_   4
#define C_   256
#define CC_  96
#define HH   128
#define WHH  128
#define HL   64
#define WL   64
#define PH   (HH*WHH)   // 16384
#define PL   (HL*WL)    // 4096

// ---- ws layout (float offsets) ----
#define WF_ENC   16
#define WF_ENC2  (WF_ENC+21600)
#define B_HRC    (WF_ENC2+7776)
#define B_LRC    (B_HRC+96)
#define B_ENC    (B_LRC+96)
#define B_ENC2   (B_ENC+25)
#define B_PROJ   (B_ENC2+9)
#define HAM_LF   (B_PROJ+96)
#define HAM_HF   (HAM_LF+25)
// bf16 weight region (u16 units, based at ws + WBF_BASE floats)
#define WBF_BASE 103488
#define WB_HRC   0
#define WB_LRC   24576
#define WB_PROJ  49152
// f32 activation scratch
#define A_CHR    140416
#define A_CHR2   (A_CHR + 6291456)
#define A_CLR    (A_CHR2 + 6291456)
#define A_MHH    (A_CLR + 1572864)
#define A_MLH    (A_MHH + 589824)
#define A_MASKLR (A_MLH + 1638400)
#define A_MLL    (A_MASKLR + 1638400)
#define A_MHL    (A_MLL + 409600)
#define A_MLRN   (A_MHL + 147456)
#define A_MHRN   (A_MLRN + 1638400)
#define A_LRUP   (A_MHRN + 589824)
#define WS_FLOATS (A_LRUP + 16777216)

// partial-sum scratch (reused regions; valid by liveness)
#define P_MHH  A_CHR2
#define P_MLH  (A_LRUP)
#define P_MLL  (A_LRUP + 7000000)
#define P_MHL  (A_LRUP + 11000000)

#define OUT0_OFF 0L
#define OUT1_OFF 1638400L
#define OUT2_OFF (1638400L + 16777216L)

__device__ __forceinline__ float ldin(const void* p, long i, int isbf) {
    if (isbf) return __bfloat162float(((const bf16*)p)[i]);
    return ((const float*)p)[i];
}

// Detect input dtype: hamming_hfqg center element == 1.0.
// (HW-verified round 6: flag==0, inputs are f32. Kept for robustness.)
__global__ void probe_dtype(const void* hamhf, int* flag) {
    const unsigned short* u = (const unsigned short*)hamhf;
    *flag = (u[4] == 0x3F80u) ? 1 : 0;
}

// Fused weight/bias conversion.
// mode 0: f32 copy. mode 2: bf16 cast into u16 region.
struct Seg { const void* src; int dst; int n; int mode; };
struct SegsN { Seg s[12]; };

__global__ __launch_bounds__(256) void cvt_all(SegsN A, float* ws,
                                               const int* __restrict__ flag, int total) {
    int isbf = *flag;
    int i = blockIdx.x * 256 + threadIdx.x;
    if (i >= total) return;
    int k = 0, j = i;
    while (j >= A.s[k].n) { j -= A.s[k].n; ++k; }
    float v = ldin(A.s[k].src, j, isbf);
    if (A.s[k].mode == 2) {
        bf16 h = __float2bfloat16(v);
        ((unsigned short*)(ws + WBF_BASE))[A.s[k].dst + j] = *(unsigned short*)&h;
    } else {
        ws[A.s[k].dst + j] = v;
    }
}

// ---------------- 1x1 conv via bf16 MFMA with on-the-fly f32->bf16 cast ----------------
// C[n][m][p] = bias[m] + sum_k W[m][k]*X[n][k][p].  M=96, K=256, per-block 256-px tile.
// LDS: X K-slice [32][pitch 260] u16 (bf16). One-step register prefetch hides HBM latency.
// Fragment layouts (m89-verified): A row=l&15, k=(l>>4)*8+j ; B col=l&15 same k ;
// D col=l&15, row=(l>>4)*4+r.
__global__ __launch_bounds__(256) void conv1x1_mfma(
    const void* __restrict__ X, const float* __restrict__ ws_base,
    int wb_off, const float* __restrict__ bias, float* __restrict__ C, int P,
    const int* __restrict__ flag)
{
    int isbf = *flag;
    const unsigned short* Wb = (const unsigned short*)(ws_base + WBF_BASE) + wb_off;
    __shared__ unsigned short lds[32 * 260];
    int t = threadIdx.x;
    int lane = t & 63, wave = t >> 6;
    int l15 = lane & 15, l4 = lane >> 4;
    int p0 = blockIdx.x * 256;
    int n = blockIdx.y;
    long Xbase = (long)n * C_ * P + p0;

    f32x4 acc[6][4];
#pragma unroll
    for (int mi = 0; mi < 6; mi++)
#pragma unroll
        for (int ni = 0; ni < 4; ni++) acc[mi][ni] = (f32x4)0.f;

    int r = t >> 3, c0 = (t & 7) * 32;   // stage: 32 channel-rows x 256 px
    long rowbase = Xbase + (long)r * P + c0;

    // prefetch ks=0 into registers (32 f32 per thread, vectorized)
    f32x4 st[8];
    if (!isbf) {
        const float* xf = (const float*)X + rowbase;
#pragma unroll
        for (int i = 0; i < 8; i++) st[i] = *(const f32x4*)(xf + i * 4);
    } else {
#pragma unroll
        for (int i = 0; i < 8; i++)
#pragma unroll
            for (int j = 0; j < 4; j++) st[i][j] = ldin(X, rowbase + i * 4 + j, isbf);
    }

    for (int ks = 0; ks < 8; ++ks) {
        // write staged registers -> LDS as bf16
        unsigned short* dst = lds + r * 260 + c0;
#pragma unroll
        for (int i = 0; i < 8; i++)
#pragma unroll
            for (int j = 0; j < 4; j++) {
                bf16 h = __float2bfloat16(st[i][j]);
                dst[i * 4 + j] = *(unsigned short*)&h;
            }
        __syncthreads();
        // issue next-slice loads; they complete under the MFMA work below
        if (ks < 7) {
            long b2 = rowbase + (long)((ks + 1) * 32) * P;
            if (!isbf) {
                const float* xf = (const float*)X + b2;
#pragma unroll
                for (int i = 0; i < 8; i++) st[i] = *(const f32x4*)(xf + i * 4);
            } else {
#pragma unroll
                for (int i = 0; i < 8; i++)
#pragma unroll
                    for (int j = 0; j < 4; j++) st[i][j] = ldin(X, b2 + i * 4 + j, isbf);
            }
        }
        short8v a[6];
#pragma unroll
        for (int mi = 0; mi < 6; mi++)
            a[mi] = *(const short8v*)(Wb + (mi * 16 + l15) * 256 + ks * 32 + l4 * 8);
#pragma unroll
        for (int ni = 0; ni < 4; ni++) {
            short8v b;
            int p = wave * 64 + ni * 16 + l15;
#pragma unroll
            for (int j = 0; j < 8; j++)
                b[j] = (short)lds[(l4 * 8 + j) * 260 + p];
#pragma unroll
            for (int mi = 0; mi < 6; mi++)
                acc[mi][ni] = __builtin_amdgcn_mfma_f32_16x16x32_bf16(a[mi], b, acc[mi][ni], 0, 0, 0);
        }
        __syncthreads();
    }
#pragma unroll
    for (int mi = 0; mi < 6; mi++)
#pragma unroll
        for (int ni = 0; ni < 4; ni++) {
            int p = p0 + wave * 64 + ni * 16 + l15;
#pragma unroll
            for (int rr = 0; rr < 4; rr++) {
                int m = mi * 16 + l4 * 4 + rr;
                C[((long)n * CC_ + m) * P + p] = acc[mi][ni][rr] + bias[m];
            }
        }
}

// ---------------- 3x3 convs (K-split direct) ----------------
template<int COUT>
__global__ __launch_bounds__(256) void conv3x3_part_k(
    const float* __restrict__ x, const float* __restrict__ Wf,
    float* __restrict__ part, int H, int W, int KC)
{
    int p = blockIdx.x * 256 + threadIdx.x;
    int n = blockIdx.y, ks = blockIdx.z;
    int HW = H * W;
    int gy = p / W, gx = p - gy * W;
    int c0 = ks * KC;
    const float* xb = x + ((long)n * CC_ + c0) * HW + p;
    float acc[COUT];
#pragma unroll
    for (int o = 0; o < COUT; o++) acc[o] = 0.f;
    for (int c = 0; c < KC; ++c) {
        const float* xc = xb + (long)c * HW;
        float v[9];
#pragma unroll
        for (int t = 0; t < 9; t++) {
            int dy = t / 3 - 1, dx = t % 3 - 1;
            int yy = gy + dy, xx = gx + dx;
            v[t] = (yy >= 0 && yy < H && xx >= 0 && xx < W) ? xc[dy * W + dx] : 0.f;
        }
        const float* wc = Wf + (c0 + c) * 9;
#pragma unroll
        for (int o = 0; o < COUT; o++)
#pragma unroll
            for (int t = 0; t < 9; t++)
                acc[o] = fmaf(wc[(long)o * CC_ * 9 + t], v[t], acc[o]);
    }
    float* pb = part + ((long)ks * N_ + n) * COUT * HW + p;
#pragma unroll
    for (int o = 0; o < COUT; o++) pb[(long)o * HW] = acc[o];
}

__global__ __launch_bounds__(256) void reduce_part(
    const float* __restrict__ part, const float* __restrict__ bias,
    float* __restrict__ out, int KS, long kstride, int COUT, int HW, int total)
{
    int g = blockIdx.x * 256 + threadIdx.x;
    if (g >= total) return;
    float s = 0.f;
    for (int k = 0; k < KS; k++) s += part[(long)k * kstride + g];
    out[g] = s + bias[(g / HW) % COUT];
}

// ---------------- CARAFE / mask kernels ----------------
__global__ __launch_bounds__(256) void carafe3_res_d(
    const float* __restrict__ x, const float* __restrict__ m,
    const float* __restrict__ hamf, float* __restrict__ y, int KC)
{
    int p = blockIdx.x * 256 + threadIdx.x;
    int n = blockIdx.y;
    int c0 = blockIdx.z * KC;
    int gy = p >> 7, gx = p & 127;
    const float* mb = m + (long)n * 9 * PH + p;
    float w[9]; float mx = -1e30f;
#pragma unroll
    for (int t = 0; t < 9; t++) { w[t] = mb[(long)t * PH]; mx = fmaxf(mx, w[t]); }
    float s = 0.f;
#pragma unroll
    for (int t = 0; t < 9; t++) { w[t] = __expf(w[t] - mx) * hamf[t]; s += w[t]; }
    float inv = 1.f / s;
#pragma unroll
    for (int t = 0; t < 9; t++) w[t] *= inv;
    for (int c = c0; c < c0 + KC; ++c) {
        const float* xc = x + ((long)n * CC_ + c) * PH + p;
        float acc = 0.f, ctr = xc[0];
#pragma unroll
        for (int t = 0; t < 9; t++) {
            int dy = t / 3 - 1, dx = t % 3 - 1;
            int yy = gy + dy, xx = gx + dx;
            float v = (yy >= 0 && yy < HH && xx >= 0 && xx < WHH) ? xc[dy * WHH + dx] : 0.f;
            acc = fmaf(v, w[t], acc);
        }
        y[((long)n * CC_ + c) * PH + p] = 2.f * ctr - acc;
    }
}

__global__ __launch_bounds__(256) void fuse_masklr(
    const float* __restrict__ mlh, const float* __restrict__ mll,
    const float* __restrict__ hamf, float* __restrict__ masklr)
{
    __shared__ float tile[25 * 144];
    int bx = blockIdx.x & 7, by = blockIdx.x >> 3;
    int n = blockIdx.y;
    int ox = threadIdx.x & 15, oy = threadIdx.x >> 4;
    int gx = bx * 16 + ox, gy = by * 16 + oy;
    const float* mb = mlh + (long)n * 25 * PH + gy * WHH + gx;
    float mv[25], w[25]; float mx = -1e30f;
#pragma unroll
    for (int t = 0; t < 25; t++) { mv[t] = mb[(long)t * PH]; mx = fmaxf(mx, mv[t]); }
    float s = 0.f;
#pragma unroll
    for (int t = 0; t < 25; t++) { w[t] = __expf(mv[t] - mx) * hamf[t]; s += w[t]; }
    float inv = 1.f / s;
#pragma unroll
    for (int t = 0; t < 25; t++) w[t] *= inv;
    int iy0 = by * 8 - 2, ix0 = bx * 8 - 2;
    const float* xn = mll + (long)n * 25 * PL;
    for (int i = threadIdx.x; i < 25 * 144; i += 256) {
        int c = i / 144, rr = i - c * 144;
        int ty = rr / 12, tx = rr - ty * 12;
        int sy = iy0 + ty, sx = ix0 + tx;
        tile[i] = (sy >= 0 && sy < HL && sx >= 0 && sx < WL) ? xn[((long)c * HL + sy) * WL + sx] : 0.f;
    }
    __syncthreads();
    int ly = oy >> 1, lx = ox >> 1;
    float* yb = masklr + (long)n * 25 * PH + gy * WHH + gx;
#pragma unroll
    for (int c = 0; c < 25; c++) {
        float acc = mv[c];
        const float* tc = tile + c * 144;
#pragma unroll
        for (int p = 0; p < 5; p++)
#pragma unroll
            for (int q = 0; q < 5; q++)
                acc = fmaf(tc[(ly + p) * 12 + lx + q], w[p * 5 + q], acc);
        yb[(long)c * PH] = acc;
    }
}

__global__ __launch_bounds__(256) void norm_lr_out(
    const float* __restrict__ masklr, const float* __restrict__ hamf,
    float* __restrict__ mlrn, float* __restrict__ out0)
{
    int g = blockIdx.x * 256 + threadIdx.x;
    int n = g / PH, p = g - n * PH;
    const float* mb = masklr + (long)n * 25 * PH + p;
    float v[25]; float mx = -1e30f;
#pragma unroll
    for (int t = 0; t < 25; t++) { v[t] = mb[(long)t * PH]; mx = fmaxf(mx, v[t]); }
    float s = 0.f;
#pragma unroll
    for (int t = 0; t < 25; t++) { v[t] = __expf(v[t] - mx) * hamf[t]; s += v[t]; }
    float inv = 1.f / s;
    float* ob = mlrn + (long)n * 25 * PH + p;
    float* o2 = out0 + (long)n * 25 * PH + p;
#pragma unroll
    for (int t = 0; t < 25; t++) {
        float rr = v[t] * inv;
        ob[(long)t * PH] = rr;
        o2[(long)t * PH] = rr;
    }
}

__global__ __launch_bounds__(256) void fuse_maskhr(
    const float* __restrict__ mhh, const float* __restrict__ mhl,
    const float* __restrict__ mlrn, const float* __restrict__ hamhf,
    float* __restrict__ mhrn)
{
    __shared__ float tile[9 * 144];
    int bx = blockIdx.x & 7, by = blockIdx.x >> 3;
    int n = blockIdx.y;
    int ox = threadIdx.x & 15, oy = threadIdx.x >> 4;
    int gx = bx * 16 + ox, gy = by * 16 + oy;
    const float* wb = mlrn + (long)n * 25 * PH + gy * WHH + gx;
    float w[25];
#pragma unroll
    for (int t = 0; t < 25; t++) w[t] = wb[(long)t * PH];
    int iy0 = by * 8 - 2, ix0 = bx * 8 - 2;
    const float* xn = mhl + (long)n * 9 * PL;
    for (int i = threadIdx.x; i < 9 * 144; i += 256) {
        int c = i / 144, rr = i - c * 144;
        int ty = rr / 12, tx = rr - ty * 12;
        int sy = iy0 + ty, sx = ix0 + tx;
        tile[i] = (sy >= 0 && sy < HL && sx >= 0 && sx < WL) ? xn[((long)c * HL + sy) * WL + sx] : 0.f;
    }
    __syncthreads();
    int ly = oy >> 1, lx = ox >> 1;
    const float* hb = mhh + (long)n * 9 * PH + gy * WHH + gx;
    float v[9]; float mx = -1e30f;
#pragma unroll
    for (int c = 0; c < 9; c++) {
        float acc = hb[(long)c * PH];
        const float* tc = tile + c * 144;
#pragma unroll
        for (int p = 0; p < 5; p++)
#pragma unroll
            for (int q = 0; q < 5; q++)
                acc = fmaf(tc[(ly + p) * 12 + lx + q], w[p * 5 + q], acc);
        v[c] = acc; mx = fmaxf(mx, acc);
    }
    float s = 0.f;
#pragma unroll
    for (int c = 0; c < 9; c++) { v[c] = __expf(v[c] - mx) * hamhf[c]; s += v[c]; }
    float inv = 1.f / s;
    float* ob = mhrn + (long)n * 9 * PH + gy * WHH + gx;
#pragma unroll
    for (int c = 0; c < 9; c++) ob[(long)c * PH] = v[c] * inv;
}

__global__ __launch_bounds__(256) void hr_out_d(
    const void* __restrict__ hr, const float* __restrict__ mhrn,
    float* __restrict__ out, long obase, const int* __restrict__ flag, int KC)
{
    int isbf = *flag;
    int p = blockIdx.x * 256 + threadIdx.x;
    int n = blockIdx.y;
    int c0 = blockIdx.z * KC;
    int gy = p >> 7, gx = p & 127;
    const float* mb = mhrn + (long)n * 9 * PH + p;
    float w[9];
#pragma unroll
    for (int t = 0; t < 9; t++) w[t] = mb[(long)t * PH];
    for (int c = c0; c < c0 + KC; ++c) {
        long cb = ((long)n * C_ + c) * PH + p;
        float ctr = ldin(hr, cb, isbf);
        float acc = 0.f;
#pragma unroll
        for (int t = 0; t < 9; t++) {
            int dy = t / 3 - 1, dx = t % 3 - 1;
            int yy = gy + dy, xx = gx + dx;
            float v = (yy >= 0 && yy < HH && xx >= 0 && xx < WHH) ? ldin(hr, cb + dy * WHH + dx, isbf) : 0.f;
            acc = fmaf(v, w[t], acc);
        }
        out[obase + cb] = 2.f * ctr - acc;
    }
}

// lr_up = carafe_up2(lr_feat, mask_lr_n) -> f32 scratch (proj conv casts internally).
__global__ __launch_bounds__(256) void lr_up_d(
    const void* __restrict__ lrf, const float* __restrict__ mlrn,
    float* __restrict__ lrup, const int* __restrict__ flag, int KC)
{
    int isbf = *flag;
    int p = blockIdx.x * 256 + threadIdx.x;
    int n = blockIdx.y;
    int c0 = blockIdx.z * KC;
    int gy = p >> 7, gx = p & 127;
    const float* wb = mlrn + (long)n * 25 * PH + p;
    float w[25];
#pragma unroll
    for (int t = 0; t < 25; t++) w[t] = wb[(long)t * PH];
    int iy0 = (gy >> 1) - 2, ix0 = (gx >> 1) - 2;
    for (int c = c0; c < c0 + KC; ++c) {
        long cb = ((long)n * C_ + c) * PL;
        float acc = 0.f;
#pragma unroll
        for (int py = 0; py < 5; py++) {
            int yy = iy0 + py;
#pragma unroll
            for (int qx = 0; qx < 5; qx++) {
                int xx = ix0 + qx;
                float v = (yy >= 0 && yy < HL && xx >= 0 && xx < WL) ? ldin(lrf, cb + yy * WL + xx, isbf) : 0.f;
                acc = fmaf(v, w[py * 5 + qx], acc);
            }
        }
        lrup[((long)n * C_ + c) * PH + p] = acc;
    }
}

extern "C" void kernel_launch(void* const* d_in, const int* in_sizes, int n_in,
                              void* d_out, int out_size, void* d_ws, size_t ws_size,
                              hipStream_t stream)
{
    if (ws_size < (size_t)WS_FLOATS * 4) return;

    const void* hr    = d_in[0];
    const void* lrf   = d_in[1];
    const void* Whrc  = d_in[2];
    const void* bhrc  = d_in[3];
    const void* Wlrc  = d_in[4];
    const void* blrc  = d_in[5];
    const void* Wenc  = d_in[6];
    const void* benc  = d_in[7];
    const void* Wenc2 = d_in[8];
    const void* benc2 = d_in[9];
    const void* Wproj = d_in[10];
    const void* bproj = d_in[11];
    const void* hamlf = d_in[12];
    const void* hamhf = d_in[13];

    float* ws = (float*)d_ws;
    int* flag = (int*)d_ws;
    float* out = (float*)d_out;

    probe_dtype<<<1, 1, 0, stream>>>(hamhf, flag);

    SegsN A;
    A.s[0]  = {Wenc,  WF_ENC,  21600, 0};
    A.s[1]  = {Wenc2, WF_ENC2, 7776,  0};
    A.s[2]  = {bhrc,  B_HRC,   96,    0};
    A.s[3]  = {blrc,  B_LRC,   96,    0};
    A.s[4]  = {benc,  B_ENC,   25,    0};
    A.s[5]  = {benc2, B_ENC2,  9,     0};
    A.s[6]  = {bproj, B_PROJ,  96,    0};
    A.s[7]  = {hamlf, HAM_LF,  25,    0};
    A.s[8]  = {hamhf, HAM_HF,  9,     0};
    A.s[9]  = {Whrc,  WB_HRC,  24576, 2};
    A.s[10] = {Wlrc,  WB_LRC,  24576, 2};
    A.s[11] = {Wproj, WB_PROJ, 24576, 2};
    int cvt_total = 21600 + 7776 + 96*3 + 25 + 9 + 25 + 9 + 24576*3;
    cvt_all<<<(cvt_total + 255) / 256, 256, 0, stream>>>(A, ws, flag, cvt_total);

    // c_hr, c_lr (1x1 compress via MFMA, f32->bf16 cast in staging)
    conv1x1_mfma<<<dim3(PH / 256, N_), 256, 0, stream>>>(hr, ws, WB_HRC, ws + B_HRC, ws + A_CHR, PH, flag);
    conv1x1_mfma<<<dim3(PL / 256, N_), 256, 0, stream>>>(lrf, ws, WB_LRC, ws + B_LRC, ws + A_CLR, PL, flag);

    // m_hh = conv3x3(c_hr, W_enc2): K-split 4 x 24ch
    conv3x3_part_k<9><<<dim3(PH / 256, N_, 4), 256, 0, stream>>>(ws + A_CHR, ws + WF_ENC2, ws + P_MHH, HH, WHH, 24);
    reduce_part<<<(N_*9*PH + 255) / 256, 256, 0, stream>>>(ws + P_MHH, ws + B_ENC2, ws + A_MHH, 4, (long)N_*9*PH, 9, PH, N_*9*PH);

    // c_hr2 = 2*c_hr - carafe3(c_hr, norm(m_hh))
    carafe3_res_d<<<dim3(PH / 256, N_, 6), 256, 0, stream>>>(ws + A_CHR, ws + A_MHH, ws + HAM_HF, ws + A_CHR2, 16);

    // m_lh = conv3x3(c_hr2, W_enc): K-split 4 x 24ch
    conv3x3_part_k<25><<<dim3(PH / 256, N_, 4), 256, 0, stream>>>(ws + A_CHR2, ws + WF_ENC, ws + P_MLH, HH, WHH, 24);
    reduce_part<<<(N_*25*PH + 255) / 256, 256, 0, stream>>>(ws + P_MLH, ws + B_ENC, ws + A_MLH, 4, (long)N_*25*PH, 25, PH, N_*25*PH);

    // m_ll, m_hl on c_lr (64x64): K-split 8 x 12ch
    conv3x3_part_k<25><<<dim3(PL / 256, N_, 8), 256, 0, stream>>>(ws + A_CLR, ws + WF_ENC, ws + P_MLL, HL, WL, 12);
    reduce_part<<<(N_*25*PL + 255) / 256, 256, 0, stream>>>(ws + P_MLL, ws + B_ENC, ws + A_MLL, 8, (long)N_*25*PL, 25, PL, N_*25*PL);
    conv3x3_part_k<9><<<dim3(PL / 256, N_, 8), 256, 0, stream>>>(ws + A_CLR, ws + WF_ENC2, ws + P_MHL, HL, WL, 12);
    reduce_part<<<(N_*9*PL + 255) / 256, 256, 0, stream>>>(ws + P_MHL, ws + B_ENC2, ws + A_MHL, 8, (long)N_*9*PL, 9, PL, N_*9*PL);

    // mask_lr = m_lh + carafe_up2(m_ll, norm(m_lh))
    fuse_masklr<<<dim3(64, N_), 256, 0, stream>>>(ws + A_MLH, ws + A_MLL, ws + HAM_LF, ws + A_MASKLR);
    // mask_lr_n (== mask_lr_init2) -> scratch f32 + output0 f32
    norm_lr_out<<<dim3(N_ * PH / 256), 256, 0, stream>>>(ws + A_MASKLR, ws + HAM_LF, ws + A_MLRN, out);
    // mask_hr_n = norm(m_hh + carafe_up2(m_hl, mask_lr_n))
    fuse_maskhr<<<dim3(64, N_), 256, 0, stream>>>(ws + A_MHH, ws + A_MHL, ws + A_MLRN, ws + HAM_HF, ws + A_MHRN);
    // hr_out -> output1
    hr_out_d<<<dim3(PH / 256, N_, 8), 256, 0, stream>>>(hr, ws + A_MHRN, out, OUT1_OFF, flag, 32);
    // lr_up = carafe_up2(lr_feat, mask_lr_n)
    lr_up_d<<<dim3(PH / 256, N_, 8), 256, 0, stream>>>(lrf, ws + A_MLRN, ws + A_LRUP, flag, 32);
    // lr_out = conv1x1(lr_up, W_proj) -> output2 (MFMA, cast in staging)
    conv1x1_mfma<<<dim3(PH / 256, N_), 256, 0, stream>>>(ws + A_LRUP, ws, WB_PROJ, ws + B_PROJ, out + OUT2_OFF, PH, flag);
}